// Round 1
// baseline (715.342 us; speedup 1.0000x reference)
//
#include <hip/hip_runtime.h>
#include <math.h>

#define N_CRIT  128
#define N_PAIRS 8128
#define N_TOT   (N_CRIT + N_PAIRS)   // 8256 floats per row
#define N_VEC4  (N_TOT / 4)          // 2064 float4 per row
#define BATCH   16384
#define MIN_W   1e-7f

// ---------------------------------------------------------------------------
// Kernel 1: build effective weight vector + weight sum. Single block so no
// cross-block sync/atomics needed. d_ws layout: float w_eff[8256]; float wsum.
// ---------------------------------------------------------------------------
__global__ __launch_bounds__(256) void prep_weights(
    const float* __restrict__ wc,     // [128]
    const float* __restrict__ wint,   // [8128]
    float* __restrict__ w_eff,        // [8256] out
    float* __restrict__ wsum)         // [1] out
{
    __shared__ float s_wc[N_CRIT];
    __shared__ float s_part[4];
    const int tid = threadIdx.x;

    float local = 0.0f;
    if (tid < N_CRIT) {
        float v   = wc[tid];
        float eff = (v < 0.0f) ? MIN_W : v;
        s_wc[tid]  = eff;
        w_eff[tid] = eff;
        local += eff;
    }
    __syncthreads();

    // pairs: p -> (i,j) with i<j, row-major upper triangle, N=128.
    // base(i) = i*(255-i)/2 ; p in [base(i), base(i+1))
    for (int p = tid; p < N_PAIRS; p += 256) {
        float disc = 65025.0f - 8.0f * (float)p;      // 255^2 - 8p
        int i = (int)((255.0f - sqrtf(disc)) * 0.5f);
        if (i < 0) i = 0;
        while (i > 0 && (i * (255 - i)) / 2 > p) --i;          // fixup down
        while (((i + 1) * (254 - i)) / 2 <= p) ++i;            // fixup up
        int j = p - (i * (255 - i)) / 2 + i + 1;
        float lower = fmaxf(-s_wc[i], -s_wc[j]);
        float w = fmaxf(wint[p], lower);
        w_eff[N_CRIT + p] = w;
        local += w;
    }

    // block reduction (4 waves of 64)
    #pragma unroll
    for (int off = 32; off > 0; off >>= 1)
        local += __shfl_down(local, off, 64);
    if ((tid & 63) == 0) s_part[tid >> 6] = local;
    __syncthreads();
    if (tid == 0)
        *wsum = s_part[0] + s_part[1] + s_part[2] + s_part[3];
}

// ---------------------------------------------------------------------------
// Kernel 2: one block per batch row. Coalesced float4 loads of the 33 KB row,
// dot with L2-resident weights, block-reduce, sigmoid((dot/wsum) - thr).
// ---------------------------------------------------------------------------
__global__ __launch_bounds__(256) void choquet_dot(
    const float* __restrict__ x,      // [BATCH, 8256]
    const float* __restrict__ w_eff,  // [8256]
    const float* __restrict__ wsum,   // [1]
    const float* __restrict__ thr,    // [1]
    float* __restrict__ out)          // [BATCH]
{
    const int row = blockIdx.x;
    const int tid = threadIdx.x;

    const float4* __restrict__ xr = (const float4*)(x + (size_t)row * N_TOT);
    const float4* __restrict__ wv = (const float4*)w_eff;

    float acc = 0.0f;
    // 2064 float4 / 256 threads: 8 full sweeps + 16-thread tail
    for (int c = tid; c < N_VEC4; c += 256) {
        float4 a = xr[c];
        float4 b = wv[c];
        acc = fmaf(a.x, b.x, acc);
        acc = fmaf(a.y, b.y, acc);
        acc = fmaf(a.z, b.z, acc);
        acc = fmaf(a.w, b.w, acc);
    }

    #pragma unroll
    for (int off = 32; off > 0; off >>= 1)
        acc += __shfl_down(acc, off, 64);

    __shared__ float s_part[4];
    if ((tid & 63) == 0) s_part[tid >> 6] = acc;
    __syncthreads();

    if (tid == 0) {
        float dot   = s_part[0] + s_part[1] + s_part[2] + s_part[3];
        float score = dot / (*wsum) - thr[0];
        out[row] = 1.0f / (1.0f + expf(-score));
    }
}

// ---------------------------------------------------------------------------
extern "C" void kernel_launch(void* const* d_in, const int* in_sizes, int n_in,
                              void* d_out, int out_size, void* d_ws, size_t ws_size,
                              hipStream_t stream) {
    const float* x    = (const float*)d_in[0];   // [16384, 8256]
    const float* wc   = (const float*)d_in[1];   // [1, 128]
    const float* wint = (const float*)d_in[2];   // [1, 8128]
    const float* thr  = (const float*)d_in[3];   // [1]
    float* out = (float*)d_out;                  // [16384]

    float* w_eff = (float*)d_ws;                 // 8256 floats
    float* wsum  = w_eff + N_TOT;                // 1 float

    prep_weights<<<1, 256, 0, stream>>>(wc, wint, w_eff, wsum);
    choquet_dot<<<BATCH, 256, 0, stream>>>(x, w_eff, wsum, thr, out);
}

// Round 3
// 685.611 us; speedup vs baseline: 1.0434x; 1.0434x over previous
//
#include <hip/hip_runtime.h>
#include <math.h>

#define N_CRIT  128
#define N_PAIRS 8128
#define N_TOT   (N_CRIT + N_PAIRS)   // 8256 floats per row
#define N_VEC4  (N_TOT / 4)          // 2064 float4 per row
#define N_FULL  2048                 // 64 lanes x 32 iters
#define BATCH   16384
#define MIN_W   1e-7f
#define ROWS_PER_BLOCK 4             // one wave per row

// native clang vector type — required by __builtin_nontemporal_load
typedef float vf4 __attribute__((ext_vector_type(4)));

// ---------------------------------------------------------------------------
// Kernel 1: build effective weight vector + 1/weight_sum. Single block.
// d_ws layout: float w_eff[8256]; float inv_wsum.
// ---------------------------------------------------------------------------
__global__ __launch_bounds__(256) void prep_weights(
    const float* __restrict__ wc,     // [128]
    const float* __restrict__ wint,   // [8128]
    float* __restrict__ w_eff,        // [8256] out
    float* __restrict__ inv_wsum)     // [1] out
{
    __shared__ float s_wc[N_CRIT];
    __shared__ float s_part[4];
    const int tid = threadIdx.x;

    float local = 0.0f;
    if (tid < N_CRIT) {
        float v   = wc[tid];
        float eff = (v < 0.0f) ? MIN_W : v;
        s_wc[tid]  = eff;
        w_eff[tid] = eff;
        local += eff;
    }
    __syncthreads();

    // pairs: p -> (i,j), i<j, row-major upper triangle, N=128.
    // base(i) = i*(255-i)/2
    for (int p = tid; p < N_PAIRS; p += 256) {
        float disc = 65025.0f - 8.0f * (float)p;      // 255^2 - 8p
        int i = (int)((255.0f - sqrtf(disc)) * 0.5f);
        if (i < 0) i = 0;
        while (i > 0 && (i * (255 - i)) / 2 > p) --i;
        while (((i + 1) * (254 - i)) / 2 <= p) ++i;
        int j = p - (i * (255 - i)) / 2 + i + 1;
        float lower = fmaxf(-s_wc[i], -s_wc[j]);
        float w = fmaxf(wint[p], lower);
        w_eff[N_CRIT + p] = w;
        local += w;
    }

    #pragma unroll
    for (int off = 32; off > 0; off >>= 1)
        local += __shfl_down(local, off, 64);
    if ((tid & 63) == 0) s_part[tid >> 6] = local;
    __syncthreads();
    if (tid == 0)
        *inv_wsum = 1.0f / (s_part[0] + s_part[1] + s_part[2] + s_part[3]);
}

// ---------------------------------------------------------------------------
// Kernel 2: one WAVE per batch row. 32 independent 16B loads per lane,
// 4 independent FMA chains, wave-only shuffle reduction (no LDS, no barrier).
// x is streamed with nontemporal loads (zero reuse); weights stay cache-hot.
// ---------------------------------------------------------------------------
__global__ __launch_bounds__(256) void choquet_dot(
    const float* __restrict__ x,        // [BATCH, 8256]
    const float* __restrict__ w_eff,    // [8256]
    const float* __restrict__ inv_wsum, // [1]
    const float* __restrict__ thr,      // [1]
    float* __restrict__ out)            // [BATCH]
{
    const int wave = threadIdx.x >> 6;
    const int lane = threadIdx.x & 63;
    const int row  = blockIdx.x * ROWS_PER_BLOCK + wave;

    const vf4* __restrict__ xr = (const vf4*)(x + (size_t)row * N_TOT);
    const vf4* __restrict__ wv = (const vf4*)w_eff;

    float a0 = 0.0f, a1 = 0.0f, a2 = 0.0f, a3 = 0.0f;

    // 2048 float4 = 32 iterations x 64 lanes, fully coalesced (1 KiB/instr)
    #pragma unroll 8
    for (int it = 0; it < N_FULL / 64; ++it) {
        const int c = lane + (it << 6);
        vf4 a = __builtin_nontemporal_load(&xr[c]);
        vf4 b = wv[c];
        a0 = fmaf(a.x, b.x, a0);
        a1 = fmaf(a.y, b.y, a1);
        a2 = fmaf(a.z, b.z, a2);
        a3 = fmaf(a.w, b.w, a3);
    }
    // tail: 2064 - 2048 = 16 float4
    if (lane < (N_VEC4 - N_FULL)) {
        const int c = N_FULL + lane;
        vf4 a = __builtin_nontemporal_load(&xr[c]);
        vf4 b = wv[c];
        a0 = fmaf(a.x, b.x, a0);
        a1 = fmaf(a.y, b.y, a1);
        a2 = fmaf(a.z, b.z, a2);
        a3 = fmaf(a.w, b.w, a3);
    }

    float acc = (a0 + a1) + (a2 + a3);
    #pragma unroll
    for (int off = 32; off > 0; off >>= 1)
        acc += __shfl_down(acc, off, 64);

    if (lane == 0) {
        float score = fmaf(acc, inv_wsum[0], -thr[0]);
        out[row] = 1.0f / (1.0f + __expf(-score));
    }
}

// ---------------------------------------------------------------------------
extern "C" void kernel_launch(void* const* d_in, const int* in_sizes, int n_in,
                              void* d_out, int out_size, void* d_ws, size_t ws_size,
                              hipStream_t stream) {
    const float* x    = (const float*)d_in[0];   // [16384, 8256]
    const float* wc   = (const float*)d_in[1];   // [1, 128]
    const float* wint = (const float*)d_in[2];   // [1, 8128]
    const float* thr  = (const float*)d_in[3];   // [1]
    float* out = (float*)d_out;                  // [16384]

    float* w_eff    = (float*)d_ws;              // 8256 floats
    float* inv_wsum = w_eff + N_TOT;             // 1 float

    prep_weights<<<1, 256, 0, stream>>>(wc, wint, w_eff, inv_wsum);
    choquet_dot<<<BATCH / ROWS_PER_BLOCK, 256, 0, stream>>>(x, w_eff, inv_wsum, thr, out);
}